// Round 2
// baseline (676.036 us; speedup 1.0000x reference)
//
#include <hip/hip_runtime.h>

// Greedy CTC decode: T=1048576 rows, V=128 labels (512 B/row), blank=0.
// Outputs concatenated float32 in d_out: [idx | keep(0/1) | path_score].
//
// 8 lanes/row, DPP cross-lane reduce. Changes vs previous version:
//  - NO register arrays anywhere: the double buffer is named scalars
//    (a0..a3 / b0..b3) with an explicit 2-step unrolled loop body, so no
//    runtime indexing can demote them to scratch (guide rule #20).
//  - __launch_bounds__(256,4): 128-VGPR budget (natural demand ~55) ->
//    regalloc has slack, guaranteed spill-free. 4 waves/SIMD = 16 waves/CU
//    is still ~5x the MLP needed to saturate HBM (~3 waves/CU suffice:
//    4KB in flight/wave vs 9.2KB/CU needed at 6.3 TB/s, 375ns latency).
// Block = 256 thr = 4 waves = 256 rows.

#define VLAB 128
#define RPB 256

// winner of a float4 chunk, columns cbase..cbase+3, first-max-wins (strict >)
__device__ __forceinline__ void chunk_amax(float4 q, int cbase, float& v, int& c) {
    float va = q.x; int ca = cbase;
    if (q.y > va) { va = q.y; ca = cbase + 1; }
    float vb = q.z; int cb = cbase + 2;
    if (q.w > vb) { vb = q.w; cb = cbase + 3; }
    v = va; c = ca;
    if (vb > va) { v = vb; c = cb; }
}

// lane-local argmax of 16 elems; pairs always (lowerCols, higherCols) with
// strict > so ties resolve to the lowest column (jnp.argmax semantics).
__device__ __forceinline__ void argmax16(float4 q0, float4 q1, float4 q2, float4 q3,
                                         int g, float& bv, int& bi) {
    const int c0 = g << 2;
    float v0, v1, v2, v3; int i0, i1, i2, i3;
    chunk_amax(q0, c0,      v0, i0);
    chunk_amax(q1, c0 + 32, v1, i1);
    chunk_amax(q2, c0 + 64, v2, i2);
    chunk_amax(q3, c0 + 96, v3, i3);
    if (v1 > v0) { v0 = v1; i0 = i1; }
    if (v3 > v2) { v2 = v3; i2 = i3; }
    bv = v0; bi = i0;
    if (v2 > v0) { bv = v2; bi = i2; }
}

// one DPP reduce round: combine with lane^k partner, tie -> lower index
template <int CTRL>
__device__ __forceinline__ void dpp_red(float& bv, int& bi) {
    const int ovb = __builtin_amdgcn_update_dpp(0, __float_as_int(bv), CTRL, 0xF, 0xF, true);
    const int oib = __builtin_amdgcn_update_dpp(0, bi, CTRL, 0xF, 0xF, true);
    const float ov = __int_as_float(ovb);
    if (ov > bv || (ov == bv && oib < bi)) { bv = ov; bi = oib; }
}

__device__ __forceinline__ void group8_reduce(float& bv, int& bi) {
    dpp_red<0xB1>(bv, bi);   // quad_perm [1,0,3,2] : xor 1
    dpp_red<0x4E>(bv, bi);   // quad_perm [2,3,0,1] : xor 2
    dpp_red<0x141>(bv, bi);  // row_half_mirror     : xor 7 within 8-lane group
}

__global__ __launch_bounds__(256, 4) void ctc_fused(const float4* __restrict__ em4,
                                                    float* __restrict__ out_idx,
                                                    float* __restrict__ out_keep,
                                                    float* __restrict__ out_score) {
    __shared__ int   s_idx[RPB + 1];
    __shared__ float s_max[RPB + 1];

    const int tid  = threadIdx.x;
    const int wave = tid >> 6;
    const int lane = tid & 63;
    const int g    = lane & 7;    // lane within 8-lane row group
    const int rsub = lane >> 3;   // row within wave-iteration (0..7)
    const int base = blockIdx.x * RPB;

    // Per-lane base pointer; iteration i reads rows base+i*32.., i.e. +i*1024 float4.
    const float4* rp = em4 + (size_t)(base + wave * 8 + rsub) * 32 + g;

    // Boundary row (base-1): loads issued first, consumed before the main
    // loop so its registers die immediately.
    const bool do_bnd = (wave == 0) && (blockIdx.x > 0);
    float4 c0, c1, c2, c3;
    if (do_bnd) {
        const float4* bp = em4 + (size_t)(base - 1) * 32 + g;
        c0 = bp[0]; c1 = bp[8]; c2 = bp[16]; c3 = bp[24];
    }

    // Prologue: iteration-0 loads (all waves).
    float4 a0 = rp[0], a1 = rp[8], a2 = rp[16], a3 = rp[24];

    if (do_bnd) {
        float bv; int bi;
        argmax16(c0, c1, c2, c3, g, bv, bi);
        group8_reduce(bv, bi);
        if (lane == 0) s_idx[0] = bi;
    } else if (blockIdx.x == 0 && tid == 0) {
        s_idx[0] = -1;  // prev of row 0
    }

    float4 b0, b1, b2, b3;
    #pragma unroll
    for (int i = 0; i < 8; i += 2) {
        {   // prefetch iteration i+1 into b
            const float4* p = rp + (size_t)(i + 1) * 1024;
            b0 = p[0]; b1 = p[8]; b2 = p[16]; b3 = p[24];
        }
        {   // process iteration i from a
            float bv; int bi;
            argmax16(a0, a1, a2, a3, g, bv, bi);
            group8_reduce(bv, bi);
            if (g == 0) {
                const int slot = i * 32 + wave * 8 + rsub + 1;
                s_idx[slot] = bi;
                s_max[slot] = bv;
            }
        }
        if (i + 2 < 8) {   // prefetch iteration i+2 into a
            const float4* p = rp + (size_t)(i + 2) * 1024;
            a0 = p[0]; a1 = p[8]; a2 = p[16]; a3 = p[24];
        }
        {   // process iteration i+1 from b
            float bv; int bi;
            argmax16(b0, b1, b2, b3, g, bv, bi);
            group8_reduce(bv, bi);
            if (g == 0) {
                const int slot = (i + 1) * 32 + wave * 8 + rsub + 1;
                s_idx[slot] = bi;
                s_max[slot] = bv;
            }
        }
    }

    __syncthreads();

    // Coalesced epilogue: one row per thread.
    const int r   = base + tid;
    const int cur = s_idx[tid + 1];
    const int prv = s_idx[tid];
    const bool keep = (cur != prv) && (cur != 0);
    out_idx[r]   = (float)cur;
    out_keep[r]  = keep ? 1.0f : 0.0f;
    out_score[r] = keep ? s_max[tid + 1] : 0.0f;
}

extern "C" void kernel_launch(void* const* d_in, const int* in_sizes, int n_in,
                              void* d_out, int out_size, void* d_ws, size_t ws_size,
                              hipStream_t stream) {
    const float* em = (const float*)d_in[0];
    const int T = in_sizes[0] / VLAB;

    float* out       = (float*)d_out;
    float* out_idx   = out;
    float* out_keep  = out + (size_t)T;
    float* out_score = out + (size_t)2 * T;

    const int grid = T / RPB;  // 4096 blocks
    ctc_fused<<<grid, RPB, 0, stream>>>(
        reinterpret_cast<const float4*>(em), out_idx, out_keep, out_score);
}